// Round 6
// baseline (883.798 us; speedup 1.0000x reference)
//
#include <hip/hip_runtime.h>
#include <math.h>

// B=8, L=1024, BL=8192, D_MODEL=256, D_INNER=512, D_STATE=16, DT_RANK=16
// Scan: 32 chunks x 32 steps; 16 s-states per thread in registers; dt folded in.

#define CH 32  // chunks
#define CT 32  // steps per chunk

typedef __attribute__((ext_vector_type(8))) short bfrag8;
typedef __attribute__((ext_vector_type(4))) float floatx4;

__device__ __forceinline__ float silu_f(float x) { return x / (1.f + __expf(-x)); }
__device__ __forceinline__ unsigned short f2bf(float x) {
    union { float f; unsigned int u; } c; c.f = x;
    unsigned int r = (c.u + 0x7fffu + ((c.u >> 16) & 1u)) >> 16;
    return (unsigned short)r;
}
__device__ __forceinline__ float bf2f(unsigned short u) {
    union { unsigned int u; float f; } c; c.u = ((unsigned int)u) << 16; return c.f;
}

// ---- fused multi-job f32->bf16 convert (zero-pads beyond n_src) ----
#define NJOBS 10
struct CvtJobs {
    const float* src[NJOBS];
    unsigned short* dst[NJOBS];
    int n_src[NJOBS];
    int n_tot[NJOBS];
    int start_blk[NJOBS + 1];
};
__global__ void conv_bf16_multi(CvtJobs J)
{
    int blk = blockIdx.x;
    int job = 0;
    while (job + 1 < NJOBS && blk >= J.start_blk[job + 1]) job++;
    int i = (blk - J.start_blk[job]) * 1024 + threadIdx.x * 4;
    if (i >= J.n_tot[job]) return;
    const float* src = J.src[job];
    unsigned short* dst = J.dst[job];
    int ns = J.n_src[job];
    if (i + 3 < ns) {
        float4 v = *(const float4*)(src + i);
        dst[i] = f2bf(v.x); dst[i+1] = f2bf(v.y); dst[i+2] = f2bf(v.z); dst[i+3] = f2bf(v.w);
    } else {
#pragma unroll
        for (int j = 0; j < 4; j++) dst[i+j] = (i+j < ns) ? f2bf(src[i+j]) : (unsigned short)0;
    }
}

// row-strided pad convert: dst[row*cd + c] = c<cs ? bf(src[row*cs+c]) : 0
__global__ void pad_bf16_kernel(const float* __restrict__ src, unsigned short* __restrict__ dst,
                                int rows, int cs, int cd)
{
    int i = blockIdx.x * 256 + threadIdx.x;
    if (i >= rows * cd) return;
    int row = i / cd, c = i - row * cd;
    dst[i] = (c < cs) ? f2bf(src[row * cs + c]) : (unsigned short)0;
}

// ---- direct-from-global MFMA GEMM, ONE WAVE per block ----
// C[M,N] = A[M,K] @ W[N,K]^T. Wave tile (16*RM) x (16*RN). K % 32 == 0.
// Branch-free pipelined k-loop: prefetch k0 while MFMA'ing k0-32.
template<int RM, int RN>
__global__ __launch_bounds__(64)
void dmfma_gemm(const unsigned short* __restrict__ A, const unsigned short* __restrict__ W,
                int K, const float* __restrict__ bias, const float* __restrict__ Cin,
                float* __restrict__ Cf32, unsigned short* __restrict__ Cbf16,
                int N, int ldc)
{
    int lane = threadIdx.x;
    int lm = lane & 15, qk = lane >> 4;
    int m0 = blockIdx.y * (16 * RM);
    int n0 = blockIdx.x * (16 * RN);

    const unsigned short* Ab = A + (size_t)(m0 + lm) * K + qk * 8;
    const unsigned short* Wb = W + (size_t)(n0 + lm) * K + qk * 8;

    floatx4 acc[RM][RN];
#pragma unroll
    for (int i = 0; i < RM; i++)
#pragma unroll
        for (int j = 0; j < RN; j++) acc[i][j] = (floatx4){0.f, 0.f, 0.f, 0.f};

    bfrag8 af[RM], wf[RN];
#pragma unroll
    for (int i = 0; i < RM; i++) af[i] = *(const bfrag8*)(Ab + (size_t)i * 16 * K);
#pragma unroll
    for (int j = 0; j < RN; j++) wf[j] = *(const bfrag8*)(Wb + (size_t)j * 16 * K);

    for (int k0 = 32; k0 < K; k0 += 32) {
        bfrag8 afn[RM], wfn[RN];
#pragma unroll
        for (int i = 0; i < RM; i++) afn[i] = *(const bfrag8*)(Ab + (size_t)i * 16 * K + k0);
#pragma unroll
        for (int j = 0; j < RN; j++) wfn[j] = *(const bfrag8*)(Wb + (size_t)j * 16 * K + k0);
#pragma unroll
        for (int i = 0; i < RM; i++)
#pragma unroll
            for (int j = 0; j < RN; j++)
                acc[i][j] = __builtin_amdgcn_mfma_f32_16x16x32_bf16(af[i], wf[j], acc[i][j], 0, 0, 0);
#pragma unroll
        for (int i = 0; i < RM; i++) af[i] = afn[i];
#pragma unroll
        for (int j = 0; j < RN; j++) wf[j] = wfn[j];
    }
#pragma unroll
    for (int i = 0; i < RM; i++)
#pragma unroll
        for (int j = 0; j < RN; j++)
            acc[i][j] = __builtin_amdgcn_mfma_f32_16x16x32_bf16(af[i], wf[j], acc[i][j], 0, 0, 0);

#pragma unroll
    for (int i = 0; i < RM; i++) {
        int mrow = m0 + i * 16 + qk * 4;
#pragma unroll
        for (int j = 0; j < RN; j++) {
            int n = n0 + j * 16 + lm;
            if (n < N) {
#pragma unroll
                for (int r = 0; r < 4; r++) {
                    float v = acc[i][j][r];
                    size_t o = (size_t)(mrow + r) * ldc + n;
                    if (bias) v += bias[n];
                    if (Cin) v += Cin[o];
                    if (Cf32) Cf32[o] = v;
                    if (Cbf16) Cbf16[o] = f2bf(v);
                }
            }
        }
    }
}

// LayerNorm over last dim (256); writes f32 and/or bf16.
__global__ void ln_kernel(const float* __restrict__ x, const float* __restrict__ g,
                          const float* __restrict__ b, float* __restrict__ yf,
                          unsigned short* __restrict__ ybf)
{
    int row = blockIdx.x;
    int tid = threadIdx.x;
    float v = x[(size_t)row * 256 + tid];
    float s1 = v, s2 = v * v;
#pragma unroll
    for (int off = 1; off < 64; off <<= 1) {
        s1 += __shfl_xor(s1, off);
        s2 += __shfl_xor(s2, off);
    }
    __shared__ float p1[4], p2[4];
    int wave = tid >> 6, lane = tid & 63;
    if (lane == 0) { p1[wave] = s1; p2[wave] = s2; }
    __syncthreads();
    float mu = (p1[0] + p1[1] + p1[2] + p1[3]) * (1.f / 256.f);
    float m2 = (p2[0] + p2[1] + p2[2] + p2[3]) * (1.f / 256.f);
    float var = m2 - mu * mu;
    float out = (v - mu) * rsqrtf(var + 1e-5f) * g[tid] + b[tid];
    if (yf) yf[(size_t)row * 256 + tid] = out;
    if (ybf) ybf[(size_t)row * 256 + tid] = f2bf(out);
}

// Causal depthwise conv (k=4) + bias + silu; xz bf16 [BL,1024] -> xc bf16.
__global__ void conv_silu_kernel(const unsigned short* __restrict__ xz, const float* __restrict__ cw,
                                 const float* __restrict__ cb, unsigned short* __restrict__ xc)
{
    int idx = blockIdx.x * 256 + threadIdx.x;
    int d = idx & 511;
    int bt = idx >> 9;
    int t = bt & 1023;
    const float* w = cw + d * 4;
    float acc = cb[d];
#pragma unroll
    for (int j = 0; j < 4; j++) {
        int tt = t + j - 3;
        if (tt >= 0) acc = fmaf(bf2f(xz[(size_t)(bt + j - 3) * 1024 + d]), w[j], acc);
    }
    xc[idx] = f2bf(silu_f(acc));
}

// ---- Chunked parallel selective scan; dt computed inline from dbl ----
// Thread = (b, d); 16 s-states in registers. Grid: b(8) x chunk(CH) x dgrp(2).
__device__ __forceinline__ float dt_inline(const float* __restrict__ row,
                                           const float* __restrict__ w, float bias)
{
    float acc = bias;
#pragma unroll
    for (int j = 0; j < 16; j++) acc = fmaf(row[j], w[j], acc);
    return fmaxf(acc, 0.f) + log1pf(__expf(-fabsf(acc)));  // softplus
}

__global__ __launch_bounds__(256)
void scan_chunk_kernel(const unsigned short* __restrict__ xc, const float* __restrict__ dbl,
                       const float* __restrict__ dtW, const float* __restrict__ dtb,
                       const float* __restrict__ A_log,
                       float* __restrict__ Pbuf, float* __restrict__ Hbuf)
{
    int bi = blockIdx.x;
    int dgrp = bi & 1;
    int chunk = (bi >> 1) & (CH - 1);
    int b = bi >> 6;
    int d = dgrp * 256 + threadIdx.x;

    float w[16];
#pragma unroll
    for (int q = 0; q < 4; q++) *(float4*)&w[q * 4] = *(const float4*)(dtW + d * 16 + q * 4);
    float dbias = dtb[d];
    float a[16];
#pragma unroll
    for (int s = 0; s < 16; s++) a[s] = -__expf(A_log[d * 16 + s]);
    float h[16], P[16];
#pragma unroll
    for (int s = 0; s < 16; s++) { h[s] = 0.f; P[s] = 1.f; }

    size_t rbt = (size_t)b * 1024 + chunk * CT;
    for (int t = 0; t < CT; t++, rbt++) {
        const float* row = dbl + rbt * 48;
        float rr[16];
#pragma unroll
        for (int q = 0; q < 4; q++) *(float4*)&rr[q * 4] = *(const float4*)(row + q * 4);
        float dt_v = dt_inline(rr, w, dbias);
        float x_v  = bf2f(xc[rbt * 512 + d]);
        float dtx = dt_v * x_v;
        float Bv[16];
#pragma unroll
        for (int q = 0; q < 4; q++) *(float4*)&Bv[q * 4] = *(const float4*)(row + 16 + q * 4);
#pragma unroll
        for (int s = 0; s < 16; s++) {
            float dA = __expf(dt_v * a[s]);
            P[s] *= dA;
            h[s] = fmaf(h[s], dA, dtx * Bv[s]);
        }
    }
    size_t base = (size_t)chunk * 65536 + ((b * 512 + d) * 16);
#pragma unroll
    for (int q = 0; q < 4; q++) {
        *(float4*)&Hbuf[base + q * 4] = *(float4*)&h[q * 4];
        *(float4*)&Pbuf[base + q * 4] = *(float4*)&P[q * 4];
    }
}

__global__ void scan_carry_kernel(const float* __restrict__ Pbuf, float* __restrict__ Hbuf)
{
    int ch = blockIdx.x * 256 + threadIdx.x;
    float h = 0.f;
#pragma unroll
    for (int c = 0; c < CH; c++) {
        float hl = Hbuf[c * 65536 + ch];
        float P  = Pbuf[c * 65536 + ch];
        Hbuf[c * 65536 + ch] = h;
        h = fmaf(P, h, hl);
    }
}

__global__ __launch_bounds__(256)
void scan_final_kernel(const unsigned short* __restrict__ xc, const float* __restrict__ dbl,
                       const float* __restrict__ dtW, const float* __restrict__ dtb,
                       const unsigned short* __restrict__ xz,
                       const float* __restrict__ A_log, const float* __restrict__ Dvec,
                       const float* __restrict__ Hbuf, unsigned short* __restrict__ y)
{
    int bi = blockIdx.x;
    int dgrp = bi & 1;
    int chunk = (bi >> 1) & (CH - 1);
    int b = bi >> 6;
    int d = dgrp * 256 + threadIdx.x;

    float w[16];
#pragma unroll
    for (int q = 0; q < 4; q++) *(float4*)&w[q * 4] = *(const float4*)(dtW + d * 16 + q * 4);
    float dbias = dtb[d];
    float a[16];
#pragma unroll
    for (int s = 0; s < 16; s++) a[s] = -__expf(A_log[d * 16 + s]);
    float dcoef = Dvec[d];

    float h[16];
    size_t base = (size_t)chunk * 65536 + ((b * 512 + d) * 16);
#pragma unroll
    for (int q = 0; q < 4; q++) *(float4*)&h[q * 4] = *(const float4*)&Hbuf[base + q * 4];

    size_t rbt = (size_t)b * 1024 + chunk * CT;
    for (int t = 0; t < CT; t++, rbt++) {
        const float* row = dbl + rbt * 48;
        float rr[16];
#pragma unroll
        for (int q = 0; q < 4; q++) *(float4*)&rr[q * 4] = *(const float4*)(row + q * 4);
        float dt_v = dt_inline(rr, w, dbias);
        float x_v  = bf2f(xc[rbt * 512 + d]);
        float z    = bf2f(xz[rbt * 1024 + 512 + d]);
        float dtx = dt_v * x_v;
        float Bv[16], Cv[16];
#pragma unroll
        for (int q = 0; q < 4; q++) *(float4*)&Bv[q * 4] = *(const float4*)(row + 16 + q * 4);
#pragma unroll
        for (int q = 0; q < 4; q++) *(float4*)&Cv[q * 4] = *(const float4*)(row + 32 + q * 4);
        float yacc = 0.f;
#pragma unroll
        for (int s = 0; s < 16; s++) {
            float dA = __expf(dt_v * a[s]);
            h[s] = fmaf(h[s], dA, dtx * Bv[s]);
            yacc = fmaf(h[s], Cv[s], yacc);
        }
        y[rbt * 512 + d] = f2bf((yacc + x_v * dcoef) * silu_f(z));
    }
}

extern "C" void kernel_launch(void* const* d_in, const int* in_sizes, int n_in,
                              void* d_out, int out_size, void* d_ws, size_t ws_size,
                              hipStream_t stream)
{
    const float* wav     = (const float*)d_in[0];
    const float* lib     = (const float*)d_in[1];
    const float* w2v_W   = (const float*)d_in[2];
    const float* w2v_b   = (const float*)d_in[3];
    const float* lib_W   = (const float*)d_in[4];
    const float* lib_b   = (const float*)d_in[5];
    const float* fuse_W  = (const float*)d_in[6];
    const float* fuse_b  = (const float*)d_in[7];
    const float* proj_W  = (const float*)d_in[8];
    const float* proj_b  = (const float*)d_in[9];
    const float* ln_g    = (const float*)d_in[10];
    const float* ln_b    = (const float*)d_in[11];
    const float* in_W    = (const float*)d_in[12];
    const float* conv_W  = (const float*)d_in[13];
    const float* conv_b  = (const float*)d_in[14];
    const float* xproj_W = (const float*)d_in[15];
    const float* dt_W    = (const float*)d_in[16];
    const float* dt_b    = (const float*)d_in[17];
    const float* A_log   = (const float*)d_in[18];
    const float* D_vec   = (const float*)d_in[19];
    const float* out_W   = (const float*)d_in[20];
    const float* fnorm_g = (const float*)d_in[21];
    const float* fnorm_b = (const float*)d_in[22];

    // ---- workspace layout ----
    char* p = (char*)d_ws;
    float* hbuf = (float*)p;             p += 8192 * 256 * 4;                  // 8 MB f32 residual
    unsigned short* xz_bf = (unsigned short*)p; p += (size_t)8192 * 1024 * 2;  // 16 MB
    float* dblb = (float*)p;             p += 8192 * 48 * 4;                   // 1.5 MB
    float* Pbuf = (float*)p;             p += (size_t)CH * 65536 * 4;          // 8 MB
    float* Hbuf = (float*)p;             p += (size_t)CH * 65536 * 4;          // 8 MB
    unsigned short* xln_bf = (unsigned short*)p; p += 8192 * 256 * 2;          // 4 MB
    unsigned short* xcb_bf = (unsigned short*)p; p += 8192 * 512 * 2;          // 8 MB
    unsigned short* yb_bf  = (unsigned short*)p; p += 8192 * 512 * 2;          // 8 MB
    unsigned short* w2vWb  = (unsigned short*)p; p += 256 * 768 * 2;
    unsigned short* fuseWb = (unsigned short*)p; p += 256 * 512 * 2;
    unsigned short* projWb = (unsigned short*)p; p += 256 * 256 * 2;
    unsigned short* inWb   = (unsigned short*)p; p += 4 * 1024 * 256 * 2;
    unsigned short* xprojWb= (unsigned short*)p; p += 4 * 64 * 512 * 2;        // padded 48->64 rows
    unsigned short* outWb  = (unsigned short*)p; p += 4 * 256 * 512 * 2;
    unsigned short* lib_bf = (unsigned short*)p; p += 8192 * 96 * 2;
    unsigned short* libWb  = (unsigned short*)p; p += 256 * 96 * 2;
    // front-end-only overlays (dead regions during front-end):
    unsigned short* wav_bf  = xcb_bf;             // 12 MB over xcb(8)+yb(8)
    unsigned short* cat_bf  = (unsigned short*)Pbuf;  // 8 MB
    unsigned short* fuse_bf = (unsigned short*)Hbuf;  // 4 MB

    dim3 blk(256);
    dim3 wblk(64);

    // ---- converts: one fused multi-job launch + 2 row-pad launches ----
    CvtJobs J;
    const float* srcs[NJOBS] = { wav, w2v_W, fuse_W, proj_W, in_W, out_W,
                                 xproj_W, xproj_W + 24576, xproj_W + 49152, xproj_W + 73728 };
    unsigned short* dsts[NJOBS] = { wav_bf, w2vWb, fuseWb, projWb, inWb, outWb,
                                    xprojWb, xprojWb + 32768, xprojWb + 65536, xprojWb + 98304 };
    int nsrc[NJOBS] = { 6291456, 196608, 131072, 65536, 1048576, 524288,
                        24576, 24576, 24576, 24576 };
    int ntot[NJOBS] = { 6291456, 196608, 131072, 65536, 1048576, 524288,
                        32768, 32768, 32768, 32768 };
    int sb = 0;
    for (int j = 0; j < NJOBS; j++) {
        J.src[j] = srcs[j]; J.dst[j] = dsts[j]; J.n_src[j] = nsrc[j]; J.n_tot[j] = ntot[j];
        J.start_blk[j] = sb; sb += ntot[j] / 1024;
    }
    J.start_blk[NJOBS] = sb;
    conv_bf16_multi<<<sb, blk, 0, stream>>>(J);
    pad_bf16_kernel<<<(8192 * 96 + 255) / 256, blk, 0, stream>>>(lib, lib_bf, 8192, 93, 96);
    pad_bf16_kernel<<<(256 * 96 + 255) / 256, blk, 0, stream>>>(lib_W, libWb, 256, 93, 96);

    // ---- front-end: all 1-wave direct-MFMA GEMMs ----
    dmfma_gemm<2,2><<<dim3(8, 256), wblk, 0, stream>>>(wav_bf, w2vWb, 768, w2v_b,
                                                       nullptr, nullptr, cat_bf, 256, 512);
    dmfma_gemm<2,2><<<dim3(8, 256), wblk, 0, stream>>>(lib_bf, libWb, 96, lib_b,
                                                       nullptr, nullptr, cat_bf + 256, 256, 512);
    dmfma_gemm<2,2><<<dim3(8, 256), wblk, 0, stream>>>(cat_bf, fuseWb, 512, fuse_b,
                                                       nullptr, nullptr, fuse_bf, 256, 256);
    dmfma_gemm<2,2><<<dim3(8, 256), wblk, 0, stream>>>(fuse_bf, projWb, 256, proj_b,
                                                       nullptr, hbuf, nullptr, 256, 256);

    for (int i = 0; i < 4; i++) {
        ln_kernel<<<8192, blk, 0, stream>>>(hbuf, ln_g + i * 256, ln_b + i * 256, nullptr, xln_bf);
        dmfma_gemm<2,4><<<dim3(16, 256), wblk, 0, stream>>>(xln_bf, inWb + (size_t)i * 262144, 256,
                                                            nullptr, nullptr, nullptr, xz_bf, 1024, 1024);
        conv_silu_kernel<<<16384, blk, 0, stream>>>(xz_bf, conv_W + i * 2048, conv_b + i * 512, xcb_bf);
        dmfma_gemm<1,2><<<dim3(2, 512), wblk, 0, stream>>>(xcb_bf, xprojWb + (size_t)i * 32768, 512,
                                                           nullptr, nullptr, dblb, nullptr, 48, 48);
        scan_chunk_kernel<<<512, blk, 0, stream>>>(xcb_bf, dblb, dt_W + i * 8192, dt_b + i * 512,
                                                   A_log + i * 8192, Pbuf, Hbuf);
        scan_carry_kernel<<<256, blk, 0, stream>>>(Pbuf, Hbuf);
        scan_final_kernel<<<512, blk, 0, stream>>>(xcb_bf, dblb, dt_W + i * 8192, dt_b + i * 512,
                                                   xz_bf, A_log + i * 8192, D_vec + i * 512,
                                                   Hbuf, yb_bf);
        dmfma_gemm<2,2><<<dim3(8, 256), wblk, 0, stream>>>(yb_bf, outWb + (size_t)i * 131072, 512,
                                                           nullptr, hbuf, hbuf, nullptr, 256, 256);
    }

    ln_kernel<<<8192, blk, 0, stream>>>(hbuf, fnorm_g, fnorm_b, (float*)d_out, nullptr);
}